// Round 1
// baseline (245.843 us; speedup 1.0000x reference)
//
#include <hip/hip_runtime.h>
#include <math.h>

#define BB      256
#define GG      4096
#define DG      256
#define DH      256
#define DZ      64
#define SPLIT   4
#define GCHUNK  (GG / SPLIT)   // 1024

// ---------------------------------------------------------------------------
// Kernel A: weighted embedding pool (partial over a G-split)
//   grid  = (B, SPLIT), block = 256
//   Each wave processes one gene at a time: lane l loads float4 (16B) of the
//   gene's 256-dim embedding row -> fully coalesced global_load_dwordx4.
// ---------------------------------------------------------------------------
__global__ __launch_bounds__(256) void pool_kernel(
    const float* __restrict__ x,      // (B, G)
    const int*   __restrict__ gi,     // (B, G)
    const float* __restrict__ emb,    // (N_GENES, 256)
    float* __restrict__ ws_pool,      // (B, SPLIT, 256) partial sums
    float* __restrict__ ws_wsum,      // (B, SPLIT)
    float* __restrict__ ws_xsum)      // (B, SPLIT)
{
    const int b    = blockIdx.x;
    const int s    = blockIdx.y;
    const int tid  = threadIdx.x;
    const int wave = tid >> 6;
    const int lane = tid & 63;

    const float* xrow = x  + (size_t)b * GG + (size_t)s * GCHUNK;
    const int*   irow = gi + (size_t)b * GG + (size_t)s * GCHUNK;
    const float4* emb4 = (const float4*)emb;   // 64 float4 per embedding row

    __shared__ float lw_s[256];
    __shared__ int   idx_s[256];
    __shared__ float accred[4][256];
    __shared__ float redw[4], redx[4];

    float wsum = 0.f, xsum = 0.f;
    float4 acc = make_float4(0.f, 0.f, 0.f, 0.f);

    for (int g0 = 0; g0 < GCHUNK; g0 += 256) {
        __syncthreads();   // protect lw_s/idx_s from previous chunk's readers
        const float xv = xrow[g0 + tid];
        const int   iv = irow[g0 + tid];
        const float lw = log1pf(xv);
        xsum += xv;
        wsum += lw;
        lw_s[tid]  = lw;
        idx_s[tid] = iv;
        __syncthreads();

        // wave w handles genes g0 + {w, w+4, w+8, ...}; lane l loads dims [4l,4l+3]
        #pragma unroll 8
        for (int k = 0; k < 64; ++k) {
            const int   gidx = (k << 2) | wave;
            const float lw_b = lw_s[gidx];                       // LDS broadcast
            const float4 e   = emb4[(size_t)idx_s[gidx] * 64 + lane];
            acc.x = fmaf(lw_b, e.x, acc.x);
            acc.y = fmaf(lw_b, e.y, acc.y);
            acc.z = fmaf(lw_b, e.z, acc.z);
            acc.w = fmaf(lw_b, e.w, acc.w);
        }
    }

    // dump per-wave float4 accumulators, reduce across the 4 waves
    accred[wave][lane * 4 + 0] = acc.x;
    accred[wave][lane * 4 + 1] = acc.y;
    accred[wave][lane * 4 + 2] = acc.z;
    accred[wave][lane * 4 + 3] = acc.w;

    // wave-level reduction of wsum / xsum (64 lanes)
    #pragma unroll
    for (int off = 32; off > 0; off >>= 1) {
        wsum += __shfl_down(wsum, off);
        xsum += __shfl_down(xsum, off);
    }
    if (lane == 0) { redw[wave] = wsum; redx[wave] = xsum; }
    __syncthreads();

    const float tot = accred[0][tid] + accred[1][tid] + accred[2][tid] + accred[3][tid];
    ws_pool[((size_t)b * SPLIT + s) * DG + tid] = tot;
    if (tid == 0) {
        ws_wsum[b * SPLIT + s] = redw[0] + redw[1] + redw[2] + redw[3];
        ws_xsum[b * SPLIT + s] = redx[0] + redx[1] + redx[2] + redx[3];
    }
}

// ---------------------------------------------------------------------------
// Kernel B: combine partials + MLP head. One block (256 threads) per row b.
// out layout: mu (B*64) | logvar (B*64) | h_pool (B*256)
// ---------------------------------------------------------------------------
__global__ __launch_bounds__(256) void mlp_kernel(
    const float* __restrict__ ws_pool,
    const float* __restrict__ ws_wsum,
    const float* __restrict__ ws_xsum,
    const float* __restrict__ W1, const float* __restrict__ b1,   // (257,256),(256)
    const float* __restrict__ W2, const float* __restrict__ b2,   // (256,256),(256)
    const float* __restrict__ Wmu, const float* __restrict__ bmu, // (256,64),(64)
    const float* __restrict__ Wlv, const float* __restrict__ blv, // (256,64),(64)
    float* __restrict__ out)
{
    const int b   = blockIdx.x;
    const int tid = threadIdx.x;

    __shared__ float h[DH + 1];   // 257
    __shared__ float h1[DH];
    __shared__ float h2[DH];

    float acc = 0.f;
    #pragma unroll
    for (int s = 0; s < SPLIT; ++s)
        acc += ws_pool[((size_t)b * SPLIT + s) * DG + tid];

    float wsum = 0.f, xsum = 0.f;
    #pragma unroll
    for (int s = 0; s < SPLIT; ++s) {
        wsum += ws_wsum[b * SPLIT + s];
        xsum += ws_xsum[b * SPLIT + s];
    }

    const float hp = acc / (wsum + 1e-8f);
    out[2 * BB * DZ + (size_t)b * DG + tid] = hp;   // h_pool output
    h[tid] = hp;
    if (tid == 0) h[DH] = log1pf(xsum);
    __syncthreads();

    // layer 1: h(257) @ W1(257,256) + b1, relu
    float a1 = b1[tid];
    for (int i = 0; i < DH + 1; ++i)
        a1 = fmaf(h[i], W1[(size_t)i * DH + tid], a1);
    h1[tid] = fmaxf(a1, 0.f);
    __syncthreads();

    // layer 2: h1(256) @ W2(256,256) + b2, relu
    float a2 = b2[tid];
    for (int i = 0; i < DH; ++i)
        a2 = fmaf(h1[i], W2[(size_t)i * DH + tid], a2);
    h2[tid] = fmaxf(a2, 0.f);
    __syncthreads();

    // heads: threads 0-63 -> mu, 64-127 -> logvar
    if (tid < 2 * DZ) {
        const bool  is_mu = (tid < DZ);
        const int   j     = tid & (DZ - 1);
        const float* Wz   = is_mu ? Wmu : Wlv;
        const float* bz   = is_mu ? bmu : blv;
        float az = bz[j];
        for (int i = 0; i < DH; ++i)
            az = fmaf(h2[i], Wz[(size_t)i * DZ + j], az);
        out[(is_mu ? 0 : BB * DZ) + (size_t)b * DZ + j] = az;
    }
}

extern "C" void kernel_launch(void* const* d_in, const int* in_sizes, int n_in,
                              void* d_out, int out_size, void* d_ws, size_t ws_size,
                              hipStream_t stream) {
    const float* x    = (const float*)d_in[0];
    const int*   gi   = (const int*)  d_in[1];
    const float* emb  = (const float*)d_in[2];
    const float* W1   = (const float*)d_in[3];
    const float* b1   = (const float*)d_in[4];
    const float* W2   = (const float*)d_in[5];
    const float* b2   = (const float*)d_in[6];
    const float* Wmu  = (const float*)d_in[7];
    const float* bmu  = (const float*)d_in[8];
    const float* Wlv  = (const float*)d_in[9];
    const float* blv  = (const float*)d_in[10];
    float* out = (float*)d_out;

    float* ws_f    = (float*)d_ws;
    float* ws_pool = ws_f;                          // B*SPLIT*256 = 262144 floats
    float* ws_wsum = ws_f + (size_t)BB * SPLIT * DG;        // +1024
    float* ws_xsum = ws_wsum + BB * SPLIT;                  // +1024

    pool_kernel<<<dim3(BB, SPLIT), 256, 0, stream>>>(x, gi, emb, ws_pool, ws_wsum, ws_xsum);
    mlp_kernel<<<BB, 256, 0, stream>>>(ws_pool, ws_wsum, ws_xsum,
                                       W1, b1, W2, b2, Wmu, bmu, Wlv, blv, out);
}

// Round 2
// 240.057 us; speedup vs baseline: 1.0241x; 1.0241x over previous
//
#include <hip/hip_runtime.h>
#include <math.h>

#define BB      256
#define GG      4096
#define DG      256
#define DH      256
#define DZ      64
#define SPLIT   8
#define GCHUNK  (GG / SPLIT)   // 512

// ---------------------------------------------------------------------------
// Kernel A: weighted embedding pool (partial over a G-split)
//   grid = (B, SPLIT) = 2048 blocks, block = 256 (4 waves) -> 8 blocks/CU,
//   32 waves/CU = 100% occupancy. Each wave processes one gene at a time:
//   lane l loads float4 of the gene's 256-dim row (global_load_dwordx4).
// ---------------------------------------------------------------------------
__global__ __launch_bounds__(256) void pool_kernel(
    const float* __restrict__ x,      // (B, G)
    const int*   __restrict__ gi,     // (B, G)
    const float* __restrict__ emb,    // (N_GENES, 256)
    float* __restrict__ ws_pool,      // (B, SPLIT, 256) partial sums
    float* __restrict__ ws_wsum,      // (B, SPLIT)
    float* __restrict__ ws_xsum)      // (B, SPLIT)
{
    const int b    = blockIdx.x;
    const int s    = blockIdx.y;
    const int tid  = threadIdx.x;
    const int wave = tid >> 6;
    const int lane = tid & 63;

    const float* xrow = x  + (size_t)b * GG + (size_t)s * GCHUNK;
    const int*   irow = gi + (size_t)b * GG + (size_t)s * GCHUNK;
    const float4* emb4 = (const float4*)emb;   // 64 float4 per embedding row

    __shared__ float lw_s[256];
    __shared__ int   idx_s[256];
    __shared__ float accred[4][256];
    __shared__ float redw[4], redx[4];

    float wsum = 0.f, xsum = 0.f;
    float4 acc = make_float4(0.f, 0.f, 0.f, 0.f);

    for (int g0 = 0; g0 < GCHUNK; g0 += 256) {
        __syncthreads();   // protect lw_s/idx_s from previous chunk's readers
        const float xv = xrow[g0 + tid];
        const int   iv = irow[g0 + tid];
        const float lw = log1pf(xv);
        xsum += xv;
        wsum += lw;
        lw_s[tid]  = lw;
        idx_s[tid] = iv;
        __syncthreads();

        // wave w handles genes g0 + {w, w+4, ...}; lane l loads dims [4l,4l+3]
        #pragma unroll 8
        for (int k = 0; k < 64; ++k) {
            const int   gidx = (k << 2) | wave;
            const float lw_b = lw_s[gidx];                       // LDS broadcast
            const float4 e   = emb4[(size_t)idx_s[gidx] * 64 + lane];
            acc.x = fmaf(lw_b, e.x, acc.x);
            acc.y = fmaf(lw_b, e.y, acc.y);
            acc.z = fmaf(lw_b, e.z, acc.z);
            acc.w = fmaf(lw_b, e.w, acc.w);
        }
    }

    // dump per-wave float4 accumulators, reduce across the 4 waves
    accred[wave][lane * 4 + 0] = acc.x;
    accred[wave][lane * 4 + 1] = acc.y;
    accred[wave][lane * 4 + 2] = acc.z;
    accred[wave][lane * 4 + 3] = acc.w;

    #pragma unroll
    for (int off = 32; off > 0; off >>= 1) {
        wsum += __shfl_down(wsum, off);
        xsum += __shfl_down(xsum, off);
    }
    if (lane == 0) { redw[wave] = wsum; redx[wave] = xsum; }
    __syncthreads();

    const float tot = accred[0][tid] + accred[1][tid] + accred[2][tid] + accred[3][tid];
    ws_pool[((size_t)b * SPLIT + s) * DG + tid] = tot;
    if (tid == 0) {
        ws_wsum[b * SPLIT + s] = redw[0] + redw[1] + redw[2] + redw[3];
        ws_xsum[b * SPLIT + s] = redx[0] + redx[1] + redx[2] + redx[3];
    }
}

// ---------------------------------------------------------------------------
// Kernel B: combine partials + MLP head. One block (512 threads) per row b.
// Each layer is a K-split-8 GEMV: kq=tid>>6 owns a K-chunk, c4=tid&63 owns
// 4 output columns via float4 weight loads; partials reduced through LDS.
// out layout: mu (B*64) | logvar (B*64) | h_pool (B*256)
// ---------------------------------------------------------------------------
__global__ __launch_bounds__(512) void mlp_kernel(
    const float* __restrict__ ws_pool,
    const float* __restrict__ ws_wsum,
    const float* __restrict__ ws_xsum,
    const float* __restrict__ W1, const float* __restrict__ b1,   // (257,256),(256)
    const float* __restrict__ W2, const float* __restrict__ b2,   // (256,256),(256)
    const float* __restrict__ Wmu, const float* __restrict__ bmu, // (256,64),(64)
    const float* __restrict__ Wlv, const float* __restrict__ blv, // (256,64),(64)
    float* __restrict__ out)
{
    const int b   = blockIdx.x;
    const int tid = threadIdx.x;
    const int kq  = tid >> 6;     // 0..7  K-chunk
    const int c4  = tid & 63;     // float4 column group

    __shared__ float  h[DH + 1];   // 257
    __shared__ float  h1[DH];
    __shared__ float  h2[DH];
    __shared__ float4 red[8][64];
    __shared__ float  redz[8][64]; // head partials: [is_lv*4+kh][j]

    // combine pool partials (threads 0..255)
    if (tid < DH) {
        float acc = 0.f;
        #pragma unroll
        for (int s = 0; s < SPLIT; ++s)
            acc += ws_pool[((size_t)b * SPLIT + s) * DG + tid];
        float wsum = 0.f, xsum = 0.f;
        #pragma unroll
        for (int s = 0; s < SPLIT; ++s) {
            wsum += ws_wsum[b * SPLIT + s];
            xsum += ws_xsum[b * SPLIT + s];
        }
        const float hp = acc / (wsum + 1e-8f);
        out[2 * BB * DZ + (size_t)b * DG + tid] = hp;   // h_pool output
        h[tid] = hp;
        if (tid == 0) h[DH] = log1pf(xsum);
    }
    __syncthreads();

    // ---- layer 1: (257) @ W1(257,256), relu ----
    {
        const float4* Wv = (const float4*)W1;
        float4 a = make_float4(0.f, 0.f, 0.f, 0.f);
        const int i0 = kq * 32;
        const int i1 = i0 + 32 + (kq == 7 ? 1 : 0);   // kq7 also covers i=256
        for (int i = i0; i < i1; ++i) {
            const float  hi = h[i];
            const float4 w  = Wv[(size_t)i * 64 + c4];
            a.x = fmaf(hi, w.x, a.x);
            a.y = fmaf(hi, w.y, a.y);
            a.z = fmaf(hi, w.z, a.z);
            a.w = fmaf(hi, w.w, a.w);
        }
        red[kq][c4] = a;
        __syncthreads();
        if (tid < 64) {
            float4 t = red[0][tid];
            #pragma unroll
            for (int s = 1; s < 8; ++s) {
                const float4 r = red[s][tid];
                t.x += r.x; t.y += r.y; t.z += r.z; t.w += r.w;
            }
            const float4 bb = ((const float4*)b1)[tid];
            h1[4 * tid + 0] = fmaxf(t.x + bb.x, 0.f);
            h1[4 * tid + 1] = fmaxf(t.y + bb.y, 0.f);
            h1[4 * tid + 2] = fmaxf(t.z + bb.z, 0.f);
            h1[4 * tid + 3] = fmaxf(t.w + bb.w, 0.f);
        }
        __syncthreads();
    }

    // ---- layer 2: (256) @ W2(256,256), relu ----
    {
        const float4* Wv = (const float4*)W2;
        float4 a = make_float4(0.f, 0.f, 0.f, 0.f);
        const int i0 = kq * 32;
        for (int i = i0; i < i0 + 32; ++i) {
            const float  hi = h1[i];
            const float4 w  = Wv[(size_t)i * 64 + c4];
            a.x = fmaf(hi, w.x, a.x);
            a.y = fmaf(hi, w.y, a.y);
            a.z = fmaf(hi, w.z, a.z);
            a.w = fmaf(hi, w.w, a.w);
        }
        red[kq][c4] = a;
        __syncthreads();
        if (tid < 64) {
            float4 t = red[0][tid];
            #pragma unroll
            for (int s = 1; s < 8; ++s) {
                const float4 r = red[s][tid];
                t.x += r.x; t.y += r.y; t.z += r.z; t.w += r.w;
            }
            const float4 bb = ((const float4*)b2)[tid];
            h2[4 * tid + 0] = fmaxf(t.x + bb.x, 0.f);
            h2[4 * tid + 1] = fmaxf(t.y + bb.y, 0.f);
            h2[4 * tid + 2] = fmaxf(t.z + bb.z, 0.f);
            h2[4 * tid + 3] = fmaxf(t.w + bb.w, 0.f);
        }
        __syncthreads();
    }

    // ---- heads: threads 0..255 -> mu, 256..511 -> lv; 4-way K-split ----
    {
        const bool is_lv = tid >= 256;
        const int  j  = tid & 63;
        const int  kh = (tid >> 6) & 3;                 // K chunk of 64
        const float* Wz = is_lv ? Wlv : Wmu;
        float az = 0.f;
        for (int i = kh * 64; i < kh * 64 + 64; ++i)
            az = fmaf(h2[i], Wz[(size_t)i * DZ + j], az);
        redz[(is_lv ? 4 : 0) + kh][j] = az;
        __syncthreads();
        if (tid < 2 * DZ) {
            const bool lv = tid >= DZ;
            const int  jj = tid & (DZ - 1);
            const int  base = lv ? 4 : 0;
            float r = redz[base][jj] + redz[base + 1][jj]
                    + redz[base + 2][jj] + redz[base + 3][jj];
            r += lv ? blv[jj] : bmu[jj];
            out[(lv ? BB * DZ : 0) + (size_t)b * DZ + jj] = r;
        }
    }
}

extern "C" void kernel_launch(void* const* d_in, const int* in_sizes, int n_in,
                              void* d_out, int out_size, void* d_ws, size_t ws_size,
                              hipStream_t stream) {
    const float* x    = (const float*)d_in[0];
    const int*   gi   = (const int*)  d_in[1];
    const float* emb  = (const float*)d_in[2];
    const float* W1   = (const float*)d_in[3];
    const float* b1   = (const float*)d_in[4];
    const float* W2   = (const float*)d_in[5];
    const float* b2   = (const float*)d_in[6];
    const float* Wmu  = (const float*)d_in[7];
    const float* bmu  = (const float*)d_in[8];
    const float* Wlv  = (const float*)d_in[9];
    const float* blv  = (const float*)d_in[10];
    float* out = (float*)d_out;

    float* ws_f    = (float*)d_ws;
    float* ws_pool = ws_f;                                  // B*SPLIT*256 floats
    float* ws_wsum = ws_f + (size_t)BB * SPLIT * DG;
    float* ws_xsum = ws_wsum + BB * SPLIT;

    pool_kernel<<<dim3(BB, SPLIT), 256, 0, stream>>>(x, gi, emb, ws_pool, ws_wsum, ws_xsum);
    mlp_kernel<<<BB, 512, 0, stream>>>(ws_pool, ws_wsum, ws_xsum,
                                       W1, b1, W2, b2, Wmu, bmu, Wlv, blv, out);
}

// Round 3
// 203.752 us; speedup vs baseline: 1.2066x; 1.1782x over previous
//
#include <hip/hip_runtime.h>
#include <math.h>

#define BB      256
#define GG      4096
#define DG      256
#define DH      256
#define DZ      64
#define SPLIT   4
#define GCHUNK  (GG / SPLIT)   // 1024
#define NGENES  30000

__device__ __forceinline__ unsigned short bf16_rn(float f) {
    unsigned u = __float_as_uint(f);
    u += 0x7FFFu + ((u >> 16) & 1u);   // round-to-nearest-even
    return (unsigned short)(u >> 16);
}

// ---------------------------------------------------------------------------
// Kernel 0: fp32 -> bf16 table conversion (grid-stride, float4 -> ushort4)
// ---------------------------------------------------------------------------
__global__ __launch_bounds__(256) void convert_kernel(
    const float* __restrict__ emb, unsigned short* __restrict__ embh, int n4)
{
    const float4*  e4 = (const float4*)emb;
    ushort4*       o4 = (ushort4*)embh;
    const int stride = gridDim.x * 256;
    for (int i = blockIdx.x * 256 + threadIdx.x; i < n4; i += stride) {
        const float4 v = e4[i];
        ushort4 o;
        o.x = bf16_rn(v.x); o.y = bf16_rn(v.y);
        o.z = bf16_rn(v.z); o.w = bf16_rn(v.w);
        o4[i] = o;
    }
}

// ---------------------------------------------------------------------------
// Kernel A (bf16 path): weighted embedding pool over a G-split.
//   grid (B, SPLIT), block 256. Wave owns one gene/iter; lane l loads uint2
//   (8 B = 4 bf16, dims 4l..4l+3) -> 512 B per gene row, halved traffic.
// ---------------------------------------------------------------------------
__global__ __launch_bounds__(256) void pool_bf16_kernel(
    const float*          __restrict__ x,
    const int*            __restrict__ gi,
    const unsigned short* __restrict__ embh,   // (NGENES, 256) bf16
    float* __restrict__ ws_pool,               // (B, SPLIT, 256)
    float* __restrict__ ws_wsum,               // (B, SPLIT)
    float* __restrict__ ws_xsum)               // (B, SPLIT)
{
    const int b    = blockIdx.x;
    const int s    = blockIdx.y;
    const int tid  = threadIdx.x;
    const int wave = tid >> 6;
    const int lane = tid & 63;

    const float* xrow = x  + (size_t)b * GG + (size_t)s * GCHUNK;
    const int*   irow = gi + (size_t)b * GG + (size_t)s * GCHUNK;
    const uint2* emb2 = (const uint2*)embh;    // 64 uint2 per 256-dim bf16 row

    __shared__ float lw_s[256];
    __shared__ int   idx_s[256];
    __shared__ float accred[4][256];
    __shared__ float redw[4], redx[4];

    float wsum = 0.f, xsum = 0.f;
    float4 acc = make_float4(0.f, 0.f, 0.f, 0.f);

    for (int g0 = 0; g0 < GCHUNK; g0 += 256) {
        __syncthreads();
        const float xv = xrow[g0 + tid];
        const int   iv = irow[g0 + tid];
        const float lw = log1pf(xv);
        xsum += xv;
        wsum += lw;
        lw_s[tid]  = lw;
        idx_s[tid] = iv;
        __syncthreads();

        #pragma unroll 8
        for (int k = 0; k < 64; ++k) {
            const int   gidx = (k << 2) | wave;
            const float lw_b = lw_s[gidx];
            const uint2 e    = emb2[(size_t)idx_s[gidx] * 64 + lane];
            acc.x = fmaf(lw_b, __uint_as_float(e.x << 16),          acc.x);
            acc.y = fmaf(lw_b, __uint_as_float(e.x & 0xFFFF0000u),  acc.y);
            acc.z = fmaf(lw_b, __uint_as_float(e.y << 16),          acc.z);
            acc.w = fmaf(lw_b, __uint_as_float(e.y & 0xFFFF0000u),  acc.w);
        }
    }

    accred[wave][lane * 4 + 0] = acc.x;
    accred[wave][lane * 4 + 1] = acc.y;
    accred[wave][lane * 4 + 2] = acc.z;
    accred[wave][lane * 4 + 3] = acc.w;

    #pragma unroll
    for (int off = 32; off > 0; off >>= 1) {
        wsum += __shfl_down(wsum, off);
        xsum += __shfl_down(xsum, off);
    }
    if (lane == 0) { redw[wave] = wsum; redx[wave] = xsum; }
    __syncthreads();

    const float tot = accred[0][tid] + accred[1][tid] + accred[2][tid] + accred[3][tid];
    ws_pool[((size_t)b * SPLIT + s) * DG + tid] = tot;
    if (tid == 0) {
        ws_wsum[b * SPLIT + s] = redw[0] + redw[1] + redw[2] + redw[3];
        ws_xsum[b * SPLIT + s] = redx[0] + redx[1] + redx[2] + redx[3];
    }
}

// ---------------------------------------------------------------------------
// Kernel A' (fallback, fp32 gather) — used only if ws_size is too small for
// the bf16 table copy.
// ---------------------------------------------------------------------------
__global__ __launch_bounds__(256) void pool_fp32_kernel(
    const float* __restrict__ x,
    const int*   __restrict__ gi,
    const float* __restrict__ emb,
    float* __restrict__ ws_pool,
    float* __restrict__ ws_wsum,
    float* __restrict__ ws_xsum)
{
    const int b    = blockIdx.x;
    const int s    = blockIdx.y;
    const int tid  = threadIdx.x;
    const int wave = tid >> 6;
    const int lane = tid & 63;

    const float* xrow = x  + (size_t)b * GG + (size_t)s * GCHUNK;
    const int*   irow = gi + (size_t)b * GG + (size_t)s * GCHUNK;
    const float4* emb4 = (const float4*)emb;

    __shared__ float lw_s[256];
    __shared__ int   idx_s[256];
    __shared__ float accred[4][256];
    __shared__ float redw[4], redx[4];

    float wsum = 0.f, xsum = 0.f;
    float4 acc = make_float4(0.f, 0.f, 0.f, 0.f);

    for (int g0 = 0; g0 < GCHUNK; g0 += 256) {
        __syncthreads();
        const float xv = xrow[g0 + tid];
        const int   iv = irow[g0 + tid];
        const float lw = log1pf(xv);
        xsum += xv;
        wsum += lw;
        lw_s[tid]  = lw;
        idx_s[tid] = iv;
        __syncthreads();

        #pragma unroll 8
        for (int k = 0; k < 64; ++k) {
            const int   gidx = (k << 2) | wave;
            const float lw_b = lw_s[gidx];
            const float4 e   = emb4[(size_t)idx_s[gidx] * 64 + lane];
            acc.x = fmaf(lw_b, e.x, acc.x);
            acc.y = fmaf(lw_b, e.y, acc.y);
            acc.z = fmaf(lw_b, e.z, acc.z);
            acc.w = fmaf(lw_b, e.w, acc.w);
        }
    }

    accred[wave][lane * 4 + 0] = acc.x;
    accred[wave][lane * 4 + 1] = acc.y;
    accred[wave][lane * 4 + 2] = acc.z;
    accred[wave][lane * 4 + 3] = acc.w;

    #pragma unroll
    for (int off = 32; off > 0; off >>= 1) {
        wsum += __shfl_down(wsum, off);
        xsum += __shfl_down(xsum, off);
    }
    if (lane == 0) { redw[wave] = wsum; redx[wave] = xsum; }
    __syncthreads();

    const float tot = accred[0][tid] + accred[1][tid] + accred[2][tid] + accred[3][tid];
    ws_pool[((size_t)b * SPLIT + s) * DG + tid] = tot;
    if (tid == 0) {
        ws_wsum[b * SPLIT + s] = redw[0] + redw[1] + redw[2] + redw[3];
        ws_xsum[b * SPLIT + s] = redx[0] + redx[1] + redx[2] + redx[3];
    }
}

// ---------------------------------------------------------------------------
// Kernel B: combine partials + MLP head. One block (512 threads) per row b.
// out layout: mu (B*64) | logvar (B*64) | h_pool (B*256)
// ---------------------------------------------------------------------------
__global__ __launch_bounds__(512) void mlp_kernel(
    const float* __restrict__ ws_pool,
    const float* __restrict__ ws_wsum,
    const float* __restrict__ ws_xsum,
    const float* __restrict__ W1, const float* __restrict__ b1,
    const float* __restrict__ W2, const float* __restrict__ b2,
    const float* __restrict__ Wmu, const float* __restrict__ bmu,
    const float* __restrict__ Wlv, const float* __restrict__ blv,
    float* __restrict__ out)
{
    const int b   = blockIdx.x;
    const int tid = threadIdx.x;
    const int kq  = tid >> 6;
    const int c4  = tid & 63;

    __shared__ float  h[DH + 1];
    __shared__ float  h1[DH];
    __shared__ float  h2[DH];
    __shared__ float4 red[8][64];
    __shared__ float  redz[8][64];

    if (tid < DH) {
        float acc = 0.f;
        #pragma unroll
        for (int s = 0; s < SPLIT; ++s)
            acc += ws_pool[((size_t)b * SPLIT + s) * DG + tid];
        float wsum = 0.f, xsum = 0.f;
        #pragma unroll
        for (int s = 0; s < SPLIT; ++s) {
            wsum += ws_wsum[b * SPLIT + s];
            xsum += ws_xsum[b * SPLIT + s];
        }
        const float hp = acc / (wsum + 1e-8f);
        out[2 * BB * DZ + (size_t)b * DG + tid] = hp;
        h[tid] = hp;
        if (tid == 0) h[DH] = log1pf(xsum);
    }
    __syncthreads();

    {   // layer 1: (257) @ W1(257,256), relu
        const float4* Wv = (const float4*)W1;
        float4 a = make_float4(0.f, 0.f, 0.f, 0.f);
        const int i0 = kq * 32;
        const int i1 = i0 + 32 + (kq == 7 ? 1 : 0);
        for (int i = i0; i < i1; ++i) {
            const float  hi = h[i];
            const float4 w  = Wv[(size_t)i * 64 + c4];
            a.x = fmaf(hi, w.x, a.x);
            a.y = fmaf(hi, w.y, a.y);
            a.z = fmaf(hi, w.z, a.z);
            a.w = fmaf(hi, w.w, a.w);
        }
        red[kq][c4] = a;
        __syncthreads();
        if (tid < 64) {
            float4 t = red[0][tid];
            #pragma unroll
            for (int s = 1; s < 8; ++s) {
                const float4 r = red[s][tid];
                t.x += r.x; t.y += r.y; t.z += r.z; t.w += r.w;
            }
            const float4 bb = ((const float4*)b1)[tid];
            h1[4 * tid + 0] = fmaxf(t.x + bb.x, 0.f);
            h1[4 * tid + 1] = fmaxf(t.y + bb.y, 0.f);
            h1[4 * tid + 2] = fmaxf(t.z + bb.z, 0.f);
            h1[4 * tid + 3] = fmaxf(t.w + bb.w, 0.f);
        }
        __syncthreads();
    }

    {   // layer 2: (256) @ W2(256,256), relu
        const float4* Wv = (const float4*)W2;
        float4 a = make_float4(0.f, 0.f, 0.f, 0.f);
        const int i0 = kq * 32;
        for (int i = i0; i < i0 + 32; ++i) {
            const float  hi = h1[i];
            const float4 w  = Wv[(size_t)i * 64 + c4];
            a.x = fmaf(hi, w.x, a.x);
            a.y = fmaf(hi, w.y, a.y);
            a.z = fmaf(hi, w.z, a.z);
            a.w = fmaf(hi, w.w, a.w);
        }
        red[kq][c4] = a;
        __syncthreads();
        if (tid < 64) {
            float4 t = red[0][tid];
            #pragma unroll
            for (int s = 1; s < 8; ++s) {
                const float4 r = red[s][tid];
                t.x += r.x; t.y += r.y; t.z += r.z; t.w += r.w;
            }
            const float4 bb = ((const float4*)b2)[tid];
            h2[4 * tid + 0] = fmaxf(t.x + bb.x, 0.f);
            h2[4 * tid + 1] = fmaxf(t.y + bb.y, 0.f);
            h2[4 * tid + 2] = fmaxf(t.z + bb.z, 0.f);
            h2[4 * tid + 3] = fmaxf(t.w + bb.w, 0.f);
        }
        __syncthreads();
    }

    {   // heads
        const bool is_lv = tid >= 256;
        const int  j  = tid & 63;
        const int  kh = (tid >> 6) & 3;
        const float* Wz = is_lv ? Wlv : Wmu;
        float az = 0.f;
        for (int i = kh * 64; i < kh * 64 + 64; ++i)
            az = fmaf(h2[i], Wz[(size_t)i * DZ + j], az);
        redz[(is_lv ? 4 : 0) + kh][j] = az;
        __syncthreads();
        if (tid < 2 * DZ) {
            const bool lv = tid >= DZ;
            const int  jj = tid & (DZ - 1);
            const int  base = lv ? 4 : 0;
            float r = redz[base][jj] + redz[base + 1][jj]
                    + redz[base + 2][jj] + redz[base + 3][jj];
            r += lv ? blv[jj] : bmu[jj];
            out[(lv ? BB * DZ : 0) + (size_t)b * DZ + jj] = r;
        }
    }
}

extern "C" void kernel_launch(void* const* d_in, const int* in_sizes, int n_in,
                              void* d_out, int out_size, void* d_ws, size_t ws_size,
                              hipStream_t stream) {
    const float* x    = (const float*)d_in[0];
    const int*   gi   = (const int*)  d_in[1];
    const float* emb  = (const float*)d_in[2];
    const float* W1   = (const float*)d_in[3];
    const float* b1   = (const float*)d_in[4];
    const float* W2   = (const float*)d_in[5];
    const float* b2   = (const float*)d_in[6];
    const float* Wmu  = (const float*)d_in[7];
    const float* bmu  = (const float*)d_in[8];
    const float* Wlv  = (const float*)d_in[9];
    const float* blv  = (const float*)d_in[10];
    float* out = (float*)d_out;

    float* ws_f    = (float*)d_ws;
    float* ws_pool = ws_f;                                   // BB*SPLIT*DG floats
    float* ws_wsum = ws_f + (size_t)BB * SPLIT * DG;         // +BB*SPLIT
    float* ws_xsum = ws_wsum + BB * SPLIT;                   // +BB*SPLIT

    const size_t base_bytes = ((size_t)BB * SPLIT * DG + 2 * BB * SPLIT) * sizeof(float);
    const size_t base_pad   = (base_bytes + 255) & ~(size_t)255;       // align 256B
    const size_t embh_bytes = (size_t)NGENES * DG * sizeof(unsigned short);
    unsigned short* embh = (unsigned short*)((char*)d_ws + base_pad);

    if (ws_size >= base_pad + embh_bytes) {
        convert_kernel<<<2048, 256, 0, stream>>>(emb, embh, NGENES * DG / 4);
        pool_bf16_kernel<<<dim3(BB, SPLIT), 256, 0, stream>>>(
            x, gi, embh, ws_pool, ws_wsum, ws_xsum);
    } else {
        pool_fp32_kernel<<<dim3(BB, SPLIT), 256, 0, stream>>>(
            x, gi, emb, ws_pool, ws_wsum, ws_xsum);
    }
    mlp_kernel<<<BB, 512, 0, stream>>>(ws_pool, ws_wsum, ws_xsum,
                                       W1, b1, W2, b2, Wmu, bmu, Wlv, blv, out);
}

// Round 4
// 175.889 us; speedup vs baseline: 1.3977x; 1.1584x over previous
//
#include <hip/hip_runtime.h>
#include <math.h>

#define BB      256
#define GG      4096
#define DG      256
#define DH      256
#define DZ      64
#define NGENES  30000
#define KPAD    30016            // NGENES padded to multiple of 32
#define NCHUNK  (KPAD / 32)      // 938 K-chunks of 32
#define KSPLIT  64
#define HALF    (KPAD / 2)       // 15008
#define FB_TILES (NCHUNK * 16)   // 15008 fragment tiles of 1 KB
// fallback (R3) path
#define SPLIT   4
#define GCHUNK  (GG / SPLIT)

typedef __attribute__((ext_vector_type(8))) short  short8v;
typedef __attribute__((ext_vector_type(4))) float  floatx4;

__device__ __forceinline__ unsigned short bf16_rn(float f) {
    unsigned u = __float_as_uint(f);
    u += 0x7FFFu + ((u >> 16) & 1u);   // round-to-nearest-even
    return (unsigned short)(u >> 16);
}

// ---------------------------------------------------------------------------
// Scatter: W[b, idx] += log1p(x).  grid (B, 2): each block owns half the K
// range in LDS (60 KB), scans the row's 4096 entries, LDS-atomic-adds the
// in-range ones, writes its half-row (incl. zero pad rows) coalesced.
// Also produces wsum[b], xsum[b] (from the h==0 block).
// ---------------------------------------------------------------------------
__global__ __launch_bounds__(256) void scatter_kernel(
    const float* __restrict__ x,
    const int*   __restrict__ gi,
    float* __restrict__ W,        // (BB, KPAD) fp32
    float* __restrict__ wsum,     // (BB)
    float* __restrict__ xsum)     // (BB)
{
    const int b   = blockIdx.x;
    const int h   = blockIdx.y;
    const int tid = threadIdx.x;
    const int base = h * HALF;

    __shared__ float sW[HALF];
    for (int i = tid; i < HALF; i += 256) sW[i] = 0.f;
    __syncthreads();

    float lws = 0.f, xs = 0.f;
    #pragma unroll 4
    for (int it = 0; it < 16; ++it) {
        const int   g  = it * 256 + tid;
        const float xv = x[(size_t)b * GG + g];
        const int   iv = gi[(size_t)b * GG + g];
        const float lw = log1pf(xv);
        lws += lw;
        xs  += xv;
        const int rel = iv - base;
        if ((unsigned)rel < (unsigned)HALF) atomicAdd(&sW[rel], lw);
    }
    __syncthreads();

    for (int i = tid; i < HALF; i += 256)
        W[(size_t)b * KPAD + base + i] = sW[i];
    __syncthreads();   // all reads of sW done; safe to reuse sW[0..7]

    #pragma unroll
    for (int off = 32; off > 0; off >>= 1) {
        lws += __shfl_down(lws, off);
        xs  += __shfl_down(xs,  off);
    }
    if ((tid & 63) == 0) { sW[tid >> 6] = lws; sW[4 + (tid >> 6)] = xs; }
    __syncthreads();
    if (tid == 0 && h == 0) {
        wsum[b] = sW[0] + sW[1] + sW[2] + sW[3];
        xsum[b] = sW[4] + sW[5] + sW[6] + sW[7];
    }
}

// ---------------------------------------------------------------------------
// fragB: emb fp32 (NGENES,256) -> bf16 in MFMA B-fragment order.
// Tile (kc, nt): 1 KB = 64 lanes x 16 B; lane holds B[k=kc*32+quad*8+j]
// [n=nt*16+(lane&15)], j=0..7.  k >= NGENES zero-padded.
// One wave per tile; grid 3752 x 256 (= 15008 waves exactly).
// ---------------------------------------------------------------------------
__global__ __launch_bounds__(256) void fragb_kernel(
    const float* __restrict__ emb, unsigned short* __restrict__ fragB)
{
    const int tile = blockIdx.x * 4 + (threadIdx.x >> 6);
    const int lane = threadIdx.x & 63;
    const int kc = tile >> 4;
    const int nt = tile & 15;
    const int n  = (nt << 4) + (lane & 15);
    const int k0 = (kc << 5) + ((lane >> 4) << 3);

    unsigned short v[8] __attribute__((aligned(16)));
    #pragma unroll
    for (int j = 0; j < 8; ++j) {
        const int k = k0 + j;
        v[j] = (k < NGENES) ? bf16_rn(emb[(size_t)k * DG + n]) : (unsigned short)0;
    }
    *(uint4*)(fragB + (size_t)tile * 512 + lane * 8) = *(const uint4*)v;
}

// ---------------------------------------------------------------------------
// GEMM: h_pool_partial = W (256 x KPAD, fp32->bf16 on the fly) @ fragB.
// grid (4 Mtiles, KSPLIT).  Block: 256 thr = 4 waves; wave w owns rows
// mt*64+w*16..+15, all 16 n-tiles; acc = 16 x float4.  B staged 16 KB/chunk
// in LDS (linear copy; fragment order preserved -> ds_read_b128).
// Partials: ws_gemm[(m*KSPLIT + ks)*256 + n].
// ---------------------------------------------------------------------------
__global__ __launch_bounds__(256) void gemm_kernel(
    const float*          __restrict__ W,
    const unsigned short* __restrict__ fragB,
    float* __restrict__ ws_gemm)
{
    const int mt   = blockIdx.x;
    const int ks   = blockIdx.y;
    const int tid  = threadIdx.x;
    const int w    = tid >> 6;
    const int lane = tid & 63;
    const int quad = lane >> 4;
    const int l16  = lane & 15;

    const int q = NCHUNK / KSPLIT;           // 14
    const int r = NCHUNK % KSPLIT;           // 42
    const int c0  = (ks < r) ? ks * (q + 1) : r * (q + 1) + (ks - r) * q;
    const int cnt = (ks < r) ? (q + 1) : q;

    __shared__ short8v sB[1024];             // 16 KB, fragment order

    const float* Arow = W + (size_t)((mt << 6) + (w << 4) + l16) * KPAD;

    floatx4 acc[16];
    #pragma unroll
    for (int nt = 0; nt < 16; ++nt) acc[nt] = (floatx4){0.f, 0.f, 0.f, 0.f};

    for (int c = 0; c < cnt; ++c) {
        const int kc = c0 + c;
        const int k0 = kc << 5;

        // A fragment: 8 consecutive fp32 of this lane's row -> bf16x8
        const float4* ap = (const float4*)(Arow + k0 + (quad << 3));
        const float4 a0 = ap[0];
        const float4 a1 = ap[1];

        // stage B chunk (16 KB linear copy, coalesced)
        const uint4* src = (const uint4*)(fragB + (size_t)kc * 8192);
        #pragma unroll
        for (int i = 0; i < 4; ++i)
            ((uint4*)sB)[i * 256 + tid] = src[i * 256 + tid];

        short8v af;
        af[0] = (short)bf16_rn(a0.x); af[1] = (short)bf16_rn(a0.y);
        af[2] = (short)bf16_rn(a0.z); af[3] = (short)bf16_rn(a0.w);
        af[4] = (short)bf16_rn(a1.x); af[5] = (short)bf16_rn(a1.y);
        af[6] = (short)bf16_rn(a1.z); af[7] = (short)bf16_rn(a1.w);

        __syncthreads();
        #pragma unroll
        for (int nt = 0; nt < 16; ++nt) {
            const short8v bf = sB[nt * 64 + lane];
            acc[nt] = __builtin_amdgcn_mfma_f32_16x16x32_bf16(af, bf, acc[nt], 0, 0, 0);
        }
        __syncthreads();
    }

    // epilogue: C/D layout col=lane&15, row=quad*4+reg (verified)
    #pragma unroll
    for (int nt = 0; nt < 16; ++nt) {
        #pragma unroll
        for (int reg = 0; reg < 4; ++reg) {
            const int m = (mt << 6) + (w << 4) + (quad << 2) + reg;
            const int n = (nt << 4) + l16;
            ws_gemm[((size_t)m * KSPLIT + ks) * DG + n] = acc[nt][reg];
        }
    }
}

// ---------------------------------------------------------------------------
// Fallback R3 kernels (used only if ws_size too small for the GEMM path)
// ---------------------------------------------------------------------------
__global__ __launch_bounds__(256) void convert_kernel(
    const float* __restrict__ emb, unsigned short* __restrict__ embh, int n4)
{
    const float4* e4 = (const float4*)emb;
    ushort4*      o4 = (ushort4*)embh;
    const int stride = gridDim.x * 256;
    for (int i = blockIdx.x * 256 + threadIdx.x; i < n4; i += stride) {
        const float4 v = e4[i];
        ushort4 o;
        o.x = bf16_rn(v.x); o.y = bf16_rn(v.y);
        o.z = bf16_rn(v.z); o.w = bf16_rn(v.w);
        o4[i] = o;
    }
}

__global__ __launch_bounds__(256) void pool_bf16_kernel(
    const float*          __restrict__ x,
    const int*            __restrict__ gi,
    const unsigned short* __restrict__ embh,
    float* __restrict__ ws_pool,
    float* __restrict__ ws_wsum,
    float* __restrict__ ws_xsum)
{
    const int b    = blockIdx.x;
    const int s    = blockIdx.y;
    const int tid  = threadIdx.x;
    const int wave = tid >> 6;
    const int lane = tid & 63;

    const float* xrow = x  + (size_t)b * GG + (size_t)s * GCHUNK;
    const int*   irow = gi + (size_t)b * GG + (size_t)s * GCHUNK;
    const uint2* emb2 = (const uint2*)embh;

    __shared__ float lw_s[256];
    __shared__ int   idx_s[256];
    __shared__ float accred[4][256];
    __shared__ float redw[4], redx[4];

    float wsum = 0.f, xsum = 0.f;
    float4 acc = make_float4(0.f, 0.f, 0.f, 0.f);

    for (int g0 = 0; g0 < GCHUNK; g0 += 256) {
        __syncthreads();
        const float xv = xrow[g0 + tid];
        const int   iv = irow[g0 + tid];
        const float lw = log1pf(xv);
        xsum += xv;
        wsum += lw;
        lw_s[tid]  = lw;
        idx_s[tid] = iv;
        __syncthreads();

        #pragma unroll 8
        for (int k = 0; k < 64; ++k) {
            const int   gidx = (k << 2) | wave;
            const float lw_b = lw_s[gidx];
            const uint2 e    = emb2[(size_t)idx_s[gidx] * 64 + lane];
            acc.x = fmaf(lw_b, __uint_as_float(e.x << 16),         acc.x);
            acc.y = fmaf(lw_b, __uint_as_float(e.x & 0xFFFF0000u), acc.y);
            acc.z = fmaf(lw_b, __uint_as_float(e.y << 16),         acc.z);
            acc.w = fmaf(lw_b, __uint_as_float(e.y & 0xFFFF0000u), acc.w);
        }
    }

    accred[wave][lane * 4 + 0] = acc.x;
    accred[wave][lane * 4 + 1] = acc.y;
    accred[wave][lane * 4 + 2] = acc.z;
    accred[wave][lane * 4 + 3] = acc.w;

    #pragma unroll
    for (int off = 32; off > 0; off >>= 1) {
        wsum += __shfl_down(wsum, off);
        xsum += __shfl_down(xsum, off);
    }
    if (lane == 0) { redw[wave] = wsum; redx[wave] = xsum; }
    __syncthreads();

    const float tot = accred[0][tid] + accred[1][tid] + accred[2][tid] + accred[3][tid];
    ws_pool[((size_t)b * SPLIT + s) * DG + tid] = tot;
    if (tid == 0) {
        ws_wsum[b * SPLIT + s] = redw[0] + redw[1] + redw[2] + redw[3];
        ws_xsum[b * SPLIT + s] = redx[0] + redx[1] + redx[2] + redx[3];
    }
}

// ---------------------------------------------------------------------------
// MLP: combine nsplit partials + normalize + 3-layer head.
// One block (512 thr) per row.  out: mu (B*64) | logvar (B*64) | h_pool (B*256)
// ---------------------------------------------------------------------------
__global__ __launch_bounds__(512) void mlp_kernel(
    const float* __restrict__ part, int nsplit,
    const float* __restrict__ wsA, const float* __restrict__ xsA, int nws,
    const float* __restrict__ W1, const float* __restrict__ b1,
    const float* __restrict__ W2, const float* __restrict__ b2,
    const float* __restrict__ Wmu, const float* __restrict__ bmu,
    const float* __restrict__ Wlv, const float* __restrict__ blv,
    float* __restrict__ out)
{
    const int b   = blockIdx.x;
    const int tid = threadIdx.x;
    const int kq  = tid >> 6;
    const int c4  = tid & 63;

    __shared__ float  h[DH + 1];
    __shared__ float  h1[DH];
    __shared__ float  h2[DH];
    __shared__ float4 red[8][64];
    __shared__ float  redz[8][64];

    if (tid < DH) {
        float acc = 0.f;
        for (int s = 0; s < nsplit; ++s)
            acc += part[((size_t)b * nsplit + s) * DG + tid];
        float wsum = 0.f, xsum = 0.f;
        for (int s = 0; s < nws; ++s) {
            wsum += wsA[b * nws + s];
            xsum += xsA[b * nws + s];
        }
        const float hp = acc / (wsum + 1e-8f);
        out[2 * BB * DZ + (size_t)b * DG + tid] = hp;
        h[tid] = hp;
        if (tid == 0) h[DH] = log1pf(xsum);
    }
    __syncthreads();

    {   // layer 1: (257) @ W1(257,256), relu
        const float4* Wv = (const float4*)W1;
        float4 a = make_float4(0.f, 0.f, 0.f, 0.f);
        const int i0 = kq * 32;
        const int i1 = i0 + 32 + (kq == 7 ? 1 : 0);
        for (int i = i0; i < i1; ++i) {
            const float  hi = h[i];
            const float4 w  = Wv[(size_t)i * 64 + c4];
            a.x = fmaf(hi, w.x, a.x);
            a.y = fmaf(hi, w.y, a.y);
            a.z = fmaf(hi, w.z, a.z);
            a.w = fmaf(hi, w.w, a.w);
        }
        red[kq][c4] = a;
        __syncthreads();
        if (tid < 64) {
            float4 t = red[0][tid];
            #pragma unroll
            for (int s = 1; s < 8; ++s) {
                const float4 rr = red[s][tid];
                t.x += rr.x; t.y += rr.y; t.z += rr.z; t.w += rr.w;
            }
            const float4 bb = ((const float4*)b1)[tid];
            h1[4 * tid + 0] = fmaxf(t.x + bb.x, 0.f);
            h1[4 * tid + 1] = fmaxf(t.y + bb.y, 0.f);
            h1[4 * tid + 2] = fmaxf(t.z + bb.z, 0.f);
            h1[4 * tid + 3] = fmaxf(t.w + bb.w, 0.f);
        }
        __syncthreads();
    }

    {   // layer 2: (256) @ W2(256,256), relu
        const float4* Wv = (const float4*)W2;
        float4 a = make_float4(0.f, 0.f, 0.f, 0.f);
        const int i0 = kq * 32;
        for (int i = i0; i < i0 + 32; ++i) {
            const float  hi = h1[i];
            const float4 w  = Wv[(size_t)i * 64 + c4];
            a.x = fmaf(hi, w.x, a.x);
            a.y = fmaf(hi, w.y, a.y);
            a.z = fmaf(hi, w.z, a.z);
            a.w = fmaf(hi, w.w, a.w);
        }
        red[kq][c4] = a;
        __syncthreads();
        if (tid < 64) {
            float4 t = red[0][tid];
            #pragma unroll
            for (int s = 1; s < 8; ++s) {
                const float4 rr = red[s][tid];
                t.x += rr.x; t.y += rr.y; t.z += rr.z; t.w += rr.w;
            }
            const float4 bb = ((const float4*)b2)[tid];
            h2[4 * tid + 0] = fmaxf(t.x + bb.x, 0.f);
            h2[4 * tid + 1] = fmaxf(t.y + bb.y, 0.f);
            h2[4 * tid + 2] = fmaxf(t.z + bb.z, 0.f);
            h2[4 * tid + 3] = fmaxf(t.w + bb.w, 0.f);
        }
        __syncthreads();
    }

    {   // heads
        const bool is_lv = tid >= 256;
        const int  j  = tid & 63;
        const int  kh = (tid >> 6) & 3;
        const float* Wz = is_lv ? Wlv : Wmu;
        float az = 0.f;
        for (int i = kh * 64; i < kh * 64 + 64; ++i)
            az = fmaf(h2[i], Wz[(size_t)i * DZ + j], az);
        redz[(is_lv ? 4 : 0) + kh][j] = az;
        __syncthreads();
        if (tid < 2 * DZ) {
            const bool lv = tid >= DZ;
            const int  jj = tid & (DZ - 1);
            const int  base = lv ? 4 : 0;
            float rr = redz[base][jj] + redz[base + 1][jj]
                     + redz[base + 2][jj] + redz[base + 3][jj];
            rr += lv ? blv[jj] : bmu[jj];
            out[(lv ? BB * DZ : 0) + (size_t)b * DZ + jj] = rr;
        }
    }
}

extern "C" void kernel_launch(void* const* d_in, const int* in_sizes, int n_in,
                              void* d_out, int out_size, void* d_ws, size_t ws_size,
                              hipStream_t stream) {
    const float* x    = (const float*)d_in[0];
    const int*   gi   = (const int*)  d_in[1];
    const float* emb  = (const float*)d_in[2];
    const float* W1   = (const float*)d_in[3];
    const float* b1   = (const float*)d_in[4];
    const float* W2   = (const float*)d_in[5];
    const float* b2   = (const float*)d_in[6];
    const float* Wmu  = (const float*)d_in[7];
    const float* bmu  = (const float*)d_in[8];
    const float* Wlv  = (const float*)d_in[9];
    const float* blv  = (const float*)d_in[10];
    float* out = (float*)d_out;

    char* ws = (char*)d_ws;
    float* ws_wsum = (float*)(ws + 0);         // <= 1024 entries
    float* ws_xsum = (float*)(ws + 4096);
    const size_t off_main = 8192;

    // full GEMM path sizes
    const size_t szW   = (size_t)BB * KPAD * sizeof(float);            // 30,736,384
    const size_t szFB  = (size_t)FB_TILES * 1024;                      // 15,368,192
    const size_t szGP  = (size_t)BB * KSPLIT * DG * sizeof(float);     // 16,777,216
    const size_t need_full = off_main + szW + szFB + szGP;

    // fallback sizes
    const size_t szPool = (size_t)BB * SPLIT * DG * sizeof(float);     // 1,048,576
    const size_t szEmbh = (size_t)NGENES * DG * sizeof(unsigned short);
    const size_t need_fb = off_main + szPool + szEmbh;

    if (ws_size >= need_full) {
        float*          Wm    = (float*)(ws + off_main);
        unsigned short* fragB = (unsigned short*)(ws + off_main + szW);
        float*          wsg   = (float*)(ws + off_main + szW + szFB);

        scatter_kernel<<<dim3(BB, 2), 256, 0, stream>>>(x, gi, Wm, ws_wsum, ws_xsum);
        fragb_kernel<<<FB_TILES / 4, 256, 0, stream>>>(emb, fragB);
        gemm_kernel<<<dim3(4, KSPLIT), 256, 0, stream>>>(Wm, fragB, wsg);
        mlp_kernel<<<BB, 512, 0, stream>>>(wsg, KSPLIT, ws_wsum, ws_xsum, 1,
                                           W1, b1, W2, b2, Wmu, bmu, Wlv, blv, out);
    } else if (ws_size >= need_fb) {
        float*          ws_pool = (float*)(ws + off_main);
        unsigned short* embh    = (unsigned short*)(ws + off_main + szPool);

        convert_kernel<<<2048, 256, 0, stream>>>(emb, embh, NGENES * DG / 4);
        pool_bf16_kernel<<<dim3(BB, SPLIT), 256, 0, stream>>>(
            x, gi, embh, ws_pool, ws_wsum, ws_xsum);
        mlp_kernel<<<BB, 512, 0, stream>>>(ws_pool, SPLIT, ws_wsum, ws_xsum, SPLIT,
                                           W1, b1, W2, b2, Wmu, bmu, Wlv, blv, out);
    }
}

// Round 5
// 165.313 us; speedup vs baseline: 1.4871x; 1.0640x over previous
//
#include <hip/hip_runtime.h>
#include <math.h>

#define BB      256
#define GG      4096
#define DG      256
#define DH      256
#define DZ      64
#define NGENES  30000
#define KPAD    30016            // NGENES padded to multiple of 32
#define NCHUNK  (KPAD / 32)      // 938 K-chunks of 32
#define KSPLIT  128
#define HALF    (KPAD / 2)       // 15008
#define FB_TILES (NCHUNK * 16)   // 15008 fragment tiles of 1 KB
// fallback (R3) path
#define SPLIT   4
#define GCHUNK  (GG / SPLIT)

typedef __attribute__((ext_vector_type(8))) short  short8v;
typedef __attribute__((ext_vector_type(4))) float  floatx4;

__device__ __forceinline__ unsigned short bf16_rn(float f) {
    unsigned u = __float_as_uint(f);
    u += 0x7FFFu + ((u >> 16) & 1u);   // round-to-nearest-even
    return (unsigned short)(u >> 16);
}

// ---------------------------------------------------------------------------
// Scatter: W16[b, idx] += log1p(x), output bf16.  grid (B, 2): each block
// owns half the K range in LDS fp32 (60 KB), scans the row, LDS-atomic-adds,
// writes its half-row as bf16 with uint4 (8-value) stores.
// ---------------------------------------------------------------------------
__global__ __launch_bounds__(256) void scatter_kernel(
    const float* __restrict__ x,
    const int*   __restrict__ gi,
    unsigned short* __restrict__ W16,  // (BB, KPAD) bf16
    float* __restrict__ wsum,          // (BB)
    float* __restrict__ xsum)          // (BB)
{
    const int b   = blockIdx.x;
    const int h   = blockIdx.y;
    const int tid = threadIdx.x;
    const int base = h * HALF;

    __shared__ float sW[HALF];
    for (int i = tid; i < HALF; i += 256) sW[i] = 0.f;
    __syncthreads();

    const float4* x4 = (const float4*)(x  + (size_t)b * GG);
    const int4*   g4 = (const int4*)  (gi + (size_t)b * GG);

    float lws = 0.f, xs = 0.f;
    #pragma unroll
    for (int it = 0; it < 4; ++it) {
        const int    e  = it * 256 + tid;
        const float4 xv = x4[e];
        const int4   iv = g4[e];
        const float lw0 = log1pf(xv.x), lw1 = log1pf(xv.y);
        const float lw2 = log1pf(xv.z), lw3 = log1pf(xv.w);
        lws += lw0 + lw1 + lw2 + lw3;
        xs  += xv.x + xv.y + xv.z + xv.w;
        int r0 = iv.x - base, r1 = iv.y - base, r2 = iv.z - base, r3 = iv.w - base;
        if ((unsigned)r0 < (unsigned)HALF) atomicAdd(&sW[r0], lw0);
        if ((unsigned)r1 < (unsigned)HALF) atomicAdd(&sW[r1], lw1);
        if ((unsigned)r2 < (unsigned)HALF) atomicAdd(&sW[r2], lw2);
        if ((unsigned)r3 < (unsigned)HALF) atomicAdd(&sW[r3], lw3);
    }
    __syncthreads();

    // write bf16, 8 values (16 B) per store
    uint4* dst = (uint4*)(W16 + (size_t)b * KPAD + base);
    for (int i = tid; i < HALF / 8; i += 256) {
        const float* s = &sW[i * 8];
        uint4 o;
        o.x = (unsigned)bf16_rn(s[0]) | ((unsigned)bf16_rn(s[1]) << 16);
        o.y = (unsigned)bf16_rn(s[2]) | ((unsigned)bf16_rn(s[3]) << 16);
        o.z = (unsigned)bf16_rn(s[4]) | ((unsigned)bf16_rn(s[5]) << 16);
        o.w = (unsigned)bf16_rn(s[6]) | ((unsigned)bf16_rn(s[7]) << 16);
        dst[i] = o;
    }
    __syncthreads();   // all reads of sW done; safe to reuse sW[0..7]

    #pragma unroll
    for (int off = 32; off > 0; off >>= 1) {
        lws += __shfl_down(lws, off);
        xs  += __shfl_down(xs,  off);
    }
    if ((tid & 63) == 0) { sW[tid >> 6] = lws; sW[4 + (tid >> 6)] = xs; }
    __syncthreads();
    if (tid == 0 && h == 0) {
        wsum[b] = sW[0] + sW[1] + sW[2] + sW[3];
        xsum[b] = sW[4] + sW[5] + sW[6] + sW[7];
    }
}

// ---------------------------------------------------------------------------
// fragB: emb fp32 (NGENES,256) -> bf16 in MFMA B-fragment order.
// Tile (kc, nt): 1 KB = 64 lanes x 16 B; lane holds B[k=kc*32+quad*8+j]
// [n=nt*16+(lane&15)], j=0..7.  k >= NGENES zero-padded.
// ---------------------------------------------------------------------------
__global__ __launch_bounds__(256) void fragb_kernel(
    const float* __restrict__ emb, unsigned short* __restrict__ fragB)
{
    const int tile = blockIdx.x * 4 + (threadIdx.x >> 6);
    const int lane = threadIdx.x & 63;
    const int kc = tile >> 4;
    const int nt = tile & 15;
    const int n  = (nt << 4) + (lane & 15);
    const int k0 = (kc << 5) + ((lane >> 4) << 3);

    unsigned short v[8] __attribute__((aligned(16)));
    #pragma unroll
    for (int j = 0; j < 8; ++j) {
        const int k = k0 + j;
        v[j] = (k < NGENES) ? bf16_rn(emb[(size_t)k * DG + n]) : (unsigned short)0;
    }
    *(uint4*)(fragB + (size_t)tile * 512 + lane * 8) = *(const uint4*)v;
}

// ---------------------------------------------------------------------------
// GEMM: h_pool_partial = W16 (256 x KPAD bf16) @ fragB.
// grid (4 Mtiles, KSPLIT=128) = 512 blocks -> 2 blocks/CU.  Block: 4 waves;
// wave w owns rows mt*64+w*16..+15, all 16 n-tiles; acc = 16 x float4.
// A-frag: single uint4 (8 bf16).  B staged 16 KB/chunk in LDS (linear copy).
// Partials: ws_gemm[(m*KSPLIT + ks)*256 + n].
// ---------------------------------------------------------------------------
__global__ __launch_bounds__(256) void gemm_kernel(
    const unsigned short* __restrict__ W16,
    const unsigned short* __restrict__ fragB,
    float* __restrict__ ws_gemm)
{
    const int mt   = blockIdx.x;
    const int ks   = blockIdx.y;
    const int tid  = threadIdx.x;
    const int w    = tid >> 6;
    const int lane = tid & 63;
    const int quad = lane >> 4;
    const int l16  = lane & 15;

    const int q = NCHUNK / KSPLIT;           // 7
    const int r = NCHUNK % KSPLIT;           // 42
    const int c0  = (ks < r) ? ks * (q + 1) : r * (q + 1) + (ks - r) * q;
    const int cnt = (ks < r) ? (q + 1) : q;

    __shared__ short8v sB[1024];             // 16 KB, fragment order

    const unsigned short* Arow =
        W16 + (size_t)((mt << 6) + (w << 4) + l16) * KPAD + (quad << 3);

    floatx4 acc[16];
    #pragma unroll
    for (int nt = 0; nt < 16; ++nt) acc[nt] = (floatx4){0.f, 0.f, 0.f, 0.f};

    for (int c = 0; c < cnt; ++c) {
        const int kc = c0 + c;

        // A fragment: 8 bf16 = one 16 B load
        const short8v af = *(const short8v*)(Arow + (kc << 5));

        // stage B chunk (16 KB linear copy, coalesced)
        const uint4* src = (const uint4*)(fragB + (size_t)kc * 8192);
        #pragma unroll
        for (int i = 0; i < 4; ++i)
            ((uint4*)sB)[i * 256 + tid] = src[i * 256 + tid];

        __syncthreads();
        #pragma unroll
        for (int nt = 0; nt < 16; ++nt) {
            const short8v bf = sB[nt * 64 + lane];
            acc[nt] = __builtin_amdgcn_mfma_f32_16x16x32_bf16(af, bf, acc[nt], 0, 0, 0);
        }
        __syncthreads();
    }

    // epilogue: C/D layout col=lane&15, row=quad*4+reg (verified)
    #pragma unroll
    for (int nt = 0; nt < 16; ++nt) {
        #pragma unroll
        for (int reg = 0; reg < 4; ++reg) {
            const int m = (mt << 6) + (w << 4) + (quad << 2) + reg;
            const int n = (nt << 4) + l16;
            ws_gemm[((size_t)m * KSPLIT + ks) * DG + n] = acc[nt][reg];
        }
    }
}

// ---------------------------------------------------------------------------
// Fallback R3 kernels (used only if ws_size too small for the GEMM path)
// ---------------------------------------------------------------------------
__global__ __launch_bounds__(256) void convert_kernel(
    const float* __restrict__ emb, unsigned short* __restrict__ embh, int n4)
{
    const float4* e4 = (const float4*)emb;
    ushort4*      o4 = (ushort4*)embh;
    const int stride = gridDim.x * 256;
    for (int i = blockIdx.x * 256 + threadIdx.x; i < n4; i += stride) {
        const float4 v = e4[i];
        ushort4 o;
        o.x = bf16_rn(v.x); o.y = bf16_rn(v.y);
        o.z = bf16_rn(v.z); o.w = bf16_rn(v.w);
        o4[i] = o;
    }
}

__global__ __launch_bounds__(256) void pool_bf16_kernel(
    const float*          __restrict__ x,
    const int*            __restrict__ gi,
    const unsigned short* __restrict__ embh,
    float* __restrict__ ws_pool,
    float* __restrict__ ws_wsum,
    float* __restrict__ ws_xsum)
{
    const int b    = blockIdx.x;
    const int s    = blockIdx.y;
    const int tid  = threadIdx.x;
    const int wave = tid >> 6;
    const int lane = tid & 63;

    const float* xrow = x  + (size_t)b * GG + (size_t)s * GCHUNK;
    const int*   irow = gi + (size_t)b * GG + (size_t)s * GCHUNK;
    const uint2* emb2 = (const uint2*)embh;

    __shared__ float lw_s[256];
    __shared__ int   idx_s[256];
    __shared__ float accred[4][256];
    __shared__ float redw[4], redx[4];

    float wsum = 0.f, xsum = 0.f;
    float4 acc = make_float4(0.f, 0.f, 0.f, 0.f);

    for (int g0 = 0; g0 < GCHUNK; g0 += 256) {
        __syncthreads();
        const float xv = xrow[g0 + tid];
        const int   iv = irow[g0 + tid];
        const float lw = log1pf(xv);
        xsum += xv;
        wsum += lw;
        lw_s[tid]  = lw;
        idx_s[tid] = iv;
        __syncthreads();

        #pragma unroll 8
        for (int k = 0; k < 64; ++k) {
            const int   gidx = (k << 2) | wave;
            const float lw_b = lw_s[gidx];
            const uint2 e    = emb2[(size_t)idx_s[gidx] * 64 + lane];
            acc.x = fmaf(lw_b, __uint_as_float(e.x << 16),         acc.x);
            acc.y = fmaf(lw_b, __uint_as_float(e.x & 0xFFFF0000u), acc.y);
            acc.z = fmaf(lw_b, __uint_as_float(e.y << 16),         acc.z);
            acc.w = fmaf(lw_b, __uint_as_float(e.y & 0xFFFF0000u), acc.w);
        }
    }

    accred[wave][lane * 4 + 0] = acc.x;
    accred[wave][lane * 4 + 1] = acc.y;
    accred[wave][lane * 4 + 2] = acc.z;
    accred[wave][lane * 4 + 3] = acc.w;

    #pragma unroll
    for (int off = 32; off > 0; off >>= 1) {
        wsum += __shfl_down(wsum, off);
        xsum += __shfl_down(xsum, off);
    }
    if (lane == 0) { redw[wave] = wsum; redx[wave] = xsum; }
    __syncthreads();

    const float tot = accred[0][tid] + accred[1][tid] + accred[2][tid] + accred[3][tid];
    ws_pool[((size_t)b * SPLIT + s) * DG + tid] = tot;
    if (tid == 0) {
        ws_wsum[b * SPLIT + s] = redw[0] + redw[1] + redw[2] + redw[3];
        ws_xsum[b * SPLIT + s] = redx[0] + redx[1] + redx[2] + redx[3];
    }
}

// ---------------------------------------------------------------------------
// MLP: combine nsplit partials + normalize + 3-layer head.
// One block (512 thr) per row.  out: mu (B*64) | logvar (B*64) | h_pool (B*256)
// ---------------------------------------------------------------------------
__global__ __launch_bounds__(512) void mlp_kernel(
    const float* __restrict__ part, int nsplit,
    const float* __restrict__ wsA, const float* __restrict__ xsA, int nws,
    const float* __restrict__ W1, const float* __restrict__ b1,
    const float* __restrict__ W2, const float* __restrict__ b2,
    const float* __restrict__ Wmu, const float* __restrict__ bmu,
    const float* __restrict__ Wlv, const float* __restrict__ blv,
    float* __restrict__ out)
{
    const int b   = blockIdx.x;
    const int tid = threadIdx.x;
    const int kq  = tid >> 6;
    const int c4  = tid & 63;

    __shared__ float  h[DH + 1];
    __shared__ float  h1[DH];
    __shared__ float  h2[DH];
    __shared__ float4 red[8][64];
    __shared__ float  redz[8][64];

    if (tid < DH) {
        float acc = 0.f;
        for (int s = 0; s < nsplit; ++s)
            acc += part[((size_t)b * nsplit + s) * DG + tid];
        float wsum = 0.f, xsum = 0.f;
        for (int s = 0; s < nws; ++s) {
            wsum += wsA[b * nws + s];
            xsum += xsA[b * nws + s];
        }
        const float hp = acc / (wsum + 1e-8f);
        out[2 * BB * DZ + (size_t)b * DG + tid] = hp;
        h[tid] = hp;
        if (tid == 0) h[DH] = log1pf(xsum);
    }
    __syncthreads();

    {   // layer 1: (257) @ W1(257,256), relu
        const float4* Wv = (const float4*)W1;
        float4 a = make_float4(0.f, 0.f, 0.f, 0.f);
        const int i0 = kq * 32;
        const int i1 = i0 + 32 + (kq == 7 ? 1 : 0);
        for (int i = i0; i < i1; ++i) {
            const float  hi = h[i];
            const float4 w  = Wv[(size_t)i * 64 + c4];
            a.x = fmaf(hi, w.x, a.x);
            a.y = fmaf(hi, w.y, a.y);
            a.z = fmaf(hi, w.z, a.z);
            a.w = fmaf(hi, w.w, a.w);
        }
        red[kq][c4] = a;
        __syncthreads();
        if (tid < 64) {
            float4 t = red[0][tid];
            #pragma unroll
            for (int s = 1; s < 8; ++s) {
                const float4 rr = red[s][tid];
                t.x += rr.x; t.y += rr.y; t.z += rr.z; t.w += rr.w;
            }
            const float4 bb = ((const float4*)b1)[tid];
            h1[4 * tid + 0] = fmaxf(t.x + bb.x, 0.f);
            h1[4 * tid + 1] = fmaxf(t.y + bb.y, 0.f);
            h1[4 * tid + 2] = fmaxf(t.z + bb.z, 0.f);
            h1[4 * tid + 3] = fmaxf(t.w + bb.w, 0.f);
        }
        __syncthreads();
    }

    {   // layer 2: (256) @ W2(256,256), relu
        const float4* Wv = (const float4*)W2;
        float4 a = make_float4(0.f, 0.f, 0.f, 0.f);
        const int i0 = kq * 32;
        for (int i = i0; i < i0 + 32; ++i) {
            const float  hi = h1[i];
            const float4 w  = Wv[(size_t)i * 64 + c4];
            a.x = fmaf(hi, w.x, a.x);
            a.y = fmaf(hi, w.y, a.y);
            a.z = fmaf(hi, w.z, a.z);
            a.w = fmaf(hi, w.w, a.w);
        }
        red[kq][c4] = a;
        __syncthreads();
        if (tid < 64) {
            float4 t = red[0][tid];
            #pragma unroll
            for (int s = 1; s < 8; ++s) {
                const float4 rr = red[s][tid];
                t.x += rr.x; t.y += rr.y; t.z += rr.z; t.w += rr.w;
            }
            const float4 bb = ((const float4*)b2)[tid];
            h2[4 * tid + 0] = fmaxf(t.x + bb.x, 0.f);
            h2[4 * tid + 1] = fmaxf(t.y + bb.y, 0.f);
            h2[4 * tid + 2] = fmaxf(t.z + bb.z, 0.f);
            h2[4 * tid + 3] = fmaxf(t.w + bb.w, 0.f);
        }
        __syncthreads();
    }

    {   // heads
        const bool is_lv = tid >= 256;
        const int  j  = tid & 63;
        const int  kh = (tid >> 6) & 3;
        const float* Wz = is_lv ? Wlv : Wmu;
        float az = 0.f;
        for (int i = kh * 64; i < kh * 64 + 64; ++i)
            az = fmaf(h2[i], Wz[(size_t)i * DZ + j], az);
        redz[(is_lv ? 4 : 0) + kh][j] = az;
        __syncthreads();
        if (tid < 2 * DZ) {
            const bool lv = tid >= DZ;
            const int  jj = tid & (DZ - 1);
            const int  base = lv ? 4 : 0;
            float rr = redz[base][jj] + redz[base + 1][jj]
                     + redz[base + 2][jj] + redz[base + 3][jj];
            rr += lv ? blv[jj] : bmu[jj];
            out[(lv ? BB * DZ : 0) + (size_t)b * DZ + jj] = rr;
        }
    }
}

extern "C" void kernel_launch(void* const* d_in, const int* in_sizes, int n_in,
                              void* d_out, int out_size, void* d_ws, size_t ws_size,
                              hipStream_t stream) {
    const float* x    = (const float*)d_in[0];
    const int*   gi   = (const int*)  d_in[1];
    const float* emb  = (const float*)d_in[2];
    const float* W1   = (const float*)d_in[3];
    const float* b1   = (const float*)d_in[4];
    const float* W2   = (const float*)d_in[5];
    const float* b2   = (const float*)d_in[6];
    const float* Wmu  = (const float*)d_in[7];
    const float* bmu  = (const float*)d_in[8];
    const float* Wlv  = (const float*)d_in[9];
    const float* blv  = (const float*)d_in[10];
    float* out = (float*)d_out;

    char* ws = (char*)d_ws;
    float* ws_wsum = (float*)(ws + 0);         // <= 1024 entries
    float* ws_xsum = (float*)(ws + 4096);
    const size_t off_main = 8192;

    // full GEMM path sizes
    const size_t szW   = (size_t)BB * KPAD * sizeof(unsigned short);   // 15,368,192
    const size_t szFB  = (size_t)FB_TILES * 1024;                      // 15,368,192
    const size_t szGP  = (size_t)BB * KSPLIT * DG * sizeof(float);     // 33,554,432
    const size_t need_full = off_main + szW + szFB + szGP;

    // fallback sizes
    const size_t szPool = (size_t)BB * SPLIT * DG * sizeof(float);
    const size_t szEmbh = (size_t)NGENES * DG * sizeof(unsigned short);
    const size_t need_fb = off_main + szPool + szEmbh;

    if (ws_size >= need_full) {
        unsigned short* Wm    = (unsigned short*)(ws + off_main);
        unsigned short* fragB = (unsigned short*)(ws + off_main + szW);
        float*          wsg   = (float*)(ws + off_main + szW + szFB);

        scatter_kernel<<<dim3(BB, 2), 256, 0, stream>>>(x, gi, Wm, ws_wsum, ws_xsum);
        fragb_kernel<<<FB_TILES / 4, 256, 0, stream>>>(emb, fragB);
        gemm_kernel<<<dim3(4, KSPLIT), 256, 0, stream>>>(Wm, fragB, wsg);
        mlp_kernel<<<BB, 512, 0, stream>>>(wsg, KSPLIT, ws_wsum, ws_xsum, 1,
                                           W1, b1, W2, b2, Wmu, bmu, Wlv, blv, out);
    } else if (ws_size >= need_fb) {
        float*          ws_pool = (float*)(ws + off_main);
        unsigned short* embh    = (unsigned short*)(ws + off_main + szPool);

        convert_kernel<<<2048, 256, 0, stream>>>(emb, embh, NGENES * DG / 4);
        pool_bf16_kernel<<<dim3(BB, SPLIT), 256, 0, stream>>>(
            x, gi, embh, ws_pool, ws_wsum, ws_xsum);
        mlp_kernel<<<BB, 512, 0, stream>>>(ws_pool, SPLIT, ws_wsum, ws_xsum, SPLIT,
                                           W1, b1, W2, b2, Wmu, bmu, Wlv, blv, out);
    }
}

// Round 6
// 143.064 us; speedup vs baseline: 1.7184x; 1.1555x over previous
//
#include <hip/hip_runtime.h>
#include <math.h>

#define BB      256
#define GG      4096
#define DG      256
#define DH      256
#define DZ      64
#define NGENES  30000
#define KPAD    30016            // NGENES padded to multiple of 32
#define NCHUNK  (KPAD / 32)      // 938 K-chunks of 32
#define KSPLIT  128
#define RED     16               // splits combined per stage-1 reduce block
#define NPART2  (KSPLIT / RED)   // 8
#define HALF    (KPAD / 2)       // 15008
#define FB_TILES (NCHUNK * 16)   // 15008 fragment tiles of 1 KB
// fallback (R3) path
#define SPLIT   4
#define GCHUNK  (GG / SPLIT)

typedef __attribute__((ext_vector_type(8))) short  short8v;
typedef __attribute__((ext_vector_type(4))) float  floatx4;

__device__ __forceinline__ unsigned short bf16_rn(float f) {
    unsigned u = __float_as_uint(f);
    u += 0x7FFFu + ((u >> 16) & 1u);   // round-to-nearest-even
    return (unsigned short)(u >> 16);
}

// ---------------------------------------------------------------------------
// Scatter: W16[b, idx] += log1p(x), output bf16.  grid (B, 2): each block
// owns half the K range in LDS fp32 (60 KB), scans the row, LDS-atomic-adds,
// writes its half-row as bf16 with uint4 (8-value) stores.
// ---------------------------------------------------------------------------
__global__ __launch_bounds__(256) void scatter_kernel(
    const float* __restrict__ x,
    const int*   __restrict__ gi,
    unsigned short* __restrict__ W16,  // (BB, KPAD) bf16
    float* __restrict__ wsum,          // (BB)
    float* __restrict__ xsum)          // (BB)
{
    const int b   = blockIdx.x;
    const int h   = blockIdx.y;
    const int tid = threadIdx.x;
    const int base = h * HALF;

    __shared__ float sW[HALF];
    for (int i = tid; i < HALF; i += 256) sW[i] = 0.f;
    __syncthreads();

    const float4* x4 = (const float4*)(x  + (size_t)b * GG);
    const int4*   g4 = (const int4*)  (gi + (size_t)b * GG);

    float lws = 0.f, xs = 0.f;
    #pragma unroll
    for (int it = 0; it < 4; ++it) {
        const int    e  = it * 256 + tid;
        const float4 xv = x4[e];
        const int4   iv = g4[e];
        const float lw0 = log1pf(xv.x), lw1 = log1pf(xv.y);
        const float lw2 = log1pf(xv.z), lw3 = log1pf(xv.w);
        lws += lw0 + lw1 + lw2 + lw3;
        xs  += xv.x + xv.y + xv.z + xv.w;
        int r0 = iv.x - base, r1 = iv.y - base, r2 = iv.z - base, r3 = iv.w - base;
        if ((unsigned)r0 < (unsigned)HALF) atomicAdd(&sW[r0], lw0);
        if ((unsigned)r1 < (unsigned)HALF) atomicAdd(&sW[r1], lw1);
        if ((unsigned)r2 < (unsigned)HALF) atomicAdd(&sW[r2], lw2);
        if ((unsigned)r3 < (unsigned)HALF) atomicAdd(&sW[r3], lw3);
    }
    __syncthreads();

    // write bf16, 8 values (16 B) per store
    uint4* dst = (uint4*)(W16 + (size_t)b * KPAD + base);
    for (int i = tid; i < HALF / 8; i += 256) {
        const float* s = &sW[i * 8];
        uint4 o;
        o.x = (unsigned)bf16_rn(s[0]) | ((unsigned)bf16_rn(s[1]) << 16);
        o.y = (unsigned)bf16_rn(s[2]) | ((unsigned)bf16_rn(s[3]) << 16);
        o.z = (unsigned)bf16_rn(s[4]) | ((unsigned)bf16_rn(s[5]) << 16);
        o.w = (unsigned)bf16_rn(s[6]) | ((unsigned)bf16_rn(s[7]) << 16);
        dst[i] = o;
    }
    __syncthreads();   // all reads of sW done; safe to reuse sW[0..7]

    #pragma unroll
    for (int off = 32; off > 0; off >>= 1) {
        lws += __shfl_down(lws, off);
        xs  += __shfl_down(xs,  off);
    }
    if ((tid & 63) == 0) { sW[tid >> 6] = lws; sW[4 + (tid >> 6)] = xs; }
    __syncthreads();
    if (tid == 0 && h == 0) {
        wsum[b] = sW[0] + sW[1] + sW[2] + sW[3];
        xsum[b] = sW[4] + sW[5] + sW[6] + sW[7];
    }
}

// ---------------------------------------------------------------------------
// fragB: emb fp32 (NGENES,256) -> bf16 in MFMA B-fragment order.
// ---------------------------------------------------------------------------
__global__ __launch_bounds__(256) void fragb_kernel(
    const float* __restrict__ emb, unsigned short* __restrict__ fragB)
{
    const int tile = blockIdx.x * 4 + (threadIdx.x >> 6);
    const int lane = threadIdx.x & 63;
    const int kc = tile >> 4;
    const int nt = tile & 15;
    const int n  = (nt << 4) + (lane & 15);
    const int k0 = (kc << 5) + ((lane >> 4) << 3);

    unsigned short v[8] __attribute__((aligned(16)));
    #pragma unroll
    for (int j = 0; j < 8; ++j) {
        const int k = k0 + j;
        v[j] = (k < NGENES) ? bf16_rn(emb[(size_t)k * DG + n]) : (unsigned short)0;
    }
    *(uint4*)(fragB + (size_t)tile * 512 + lane * 8) = *(const uint4*)v;
}

// ---------------------------------------------------------------------------
// GEMM: h_pool_partial = W16 (256 x KPAD bf16) @ fragB.
// grid (4 Mtiles, KSPLIT=128) = 512 blocks -> 2 blocks/CU.
// Partials: ws_gemm[(m*KSPLIT + ks)*256 + n].
// ---------------------------------------------------------------------------
__global__ __launch_bounds__(256) void gemm_kernel(
    const unsigned short* __restrict__ W16,
    const unsigned short* __restrict__ fragB,
    float* __restrict__ ws_gemm)
{
    const int mt   = blockIdx.x;
    const int ks   = blockIdx.y;
    const int tid  = threadIdx.x;
    const int w    = tid >> 6;
    const int lane = tid & 63;
    const int quad = lane >> 4;
    const int l16  = lane & 15;

    const int q = NCHUNK / KSPLIT;           // 7
    const int r = NCHUNK % KSPLIT;           // 42
    const int c0  = (ks < r) ? ks * (q + 1) : r * (q + 1) + (ks - r) * q;
    const int cnt = (ks < r) ? (q + 1) : q;

    __shared__ short8v sB[1024];             // 16 KB, fragment order

    const unsigned short* Arow =
        W16 + (size_t)((mt << 6) + (w << 4) + l16) * KPAD + (quad << 3);

    floatx4 acc[16];
    #pragma unroll
    for (int nt = 0; nt < 16; ++nt) acc[nt] = (floatx4){0.f, 0.f, 0.f, 0.f};

    for (int c = 0; c < cnt; ++c) {
        const int kc = c0 + c;

        // A fragment: 8 bf16 = one 16 B load
        const short8v af = *(const short8v*)(Arow + (kc << 5));

        // stage B chunk (16 KB linear copy, coalesced)
        const uint4* src = (const uint4*)(fragB + (size_t)kc * 8192);
        #pragma unroll
        for (int i = 0; i < 4; ++i)
            ((uint4*)sB)[i * 256 + tid] = src[i * 256 + tid];

        __syncthreads();
        #pragma unroll
        for (int nt = 0; nt < 16; ++nt) {
            const short8v bf = sB[nt * 64 + lane];
            acc[nt] = __builtin_amdgcn_mfma_f32_16x16x32_bf16(af, bf, acc[nt], 0, 0, 0);
        }
        __syncthreads();
    }

    // epilogue: C/D layout col=lane&15, row=quad*4+reg (verified)
    #pragma unroll
    for (int nt = 0; nt < 16; ++nt) {
        #pragma unroll
        for (int reg = 0; reg < 4; ++reg) {
            const int m = (mt << 6) + (w << 4) + (quad << 2) + reg;
            const int n = (nt << 4) + l16;
            ws_gemm[((size_t)m * KSPLIT + ks) * DG + n] = acc[nt][reg];
        }
    }
}

// ---------------------------------------------------------------------------
// Stage-1 reduce: 128 partials -> 8.  grid (BB, NPART2) = 2048 blocks,
// 256 thr.  Block (b,p) sums ks in [p*RED, (p+1)*RED); thread d is column d.
// All loads coalesced (1 KB rows), trip count compile-time -> unrolled,
// 16 independent loads in flight.
// ---------------------------------------------------------------------------
__global__ __launch_bounds__(256) void reduce_kernel(
    const float* __restrict__ wsg, float* __restrict__ part2)
{
    const int b = blockIdx.x, p = blockIdx.y, d = threadIdx.x;
    const float* src = wsg + ((size_t)b * KSPLIT + p * RED) * DG + d;
    float s = 0.f;
    #pragma unroll
    for (int i = 0; i < RED; ++i) s += src[(size_t)i * DG];
    part2[((size_t)b * NPART2 + p) * DG + d] = s;
}

// ---------------------------------------------------------------------------
// Fallback R3 kernels (used only if ws_size too small for the GEMM path)
// ---------------------------------------------------------------------------
__global__ __launch_bounds__(256) void convert_kernel(
    const float* __restrict__ emb, unsigned short* __restrict__ embh, int n4)
{
    const float4* e4 = (const float4*)emb;
    ushort4*      o4 = (ushort4*)embh;
    const int stride = gridDim.x * 256;
    for (int i = blockIdx.x * 256 + threadIdx.x; i < n4; i += stride) {
        const float4 v = e4[i];
        ushort4 o;
        o.x = bf16_rn(v.x); o.y = bf16_rn(v.y);
        o.z = bf16_rn(v.z); o.w = bf16_rn(v.w);
        o4[i] = o;
    }
}

__global__ __launch_bounds__(256) void pool_bf16_kernel(
    const float*          __restrict__ x,
    const int*            __restrict__ gi,
    const unsigned short* __restrict__ embh,
    float* __restrict__ ws_pool,
    float* __restrict__ ws_wsum,
    float* __restrict__ ws_xsum)
{
    const int b    = blockIdx.x;
    const int s    = blockIdx.y;
    const int tid  = threadIdx.x;
    const int wave = tid >> 6;
    const int lane = tid & 63;

    const float* xrow = x  + (size_t)b * GG + (size_t)s * GCHUNK;
    const int*   irow = gi + (size_t)b * GG + (size_t)s * GCHUNK;
    const uint2* emb2 = (const uint2*)embh;

    __shared__ float lw_s[256];
    __shared__ int   idx_s[256];
    __shared__ float accred[4][256];
    __shared__ float redw[4], redx[4];

    float wsum = 0.f, xsum = 0.f;
    float4 acc = make_float4(0.f, 0.f, 0.f, 0.f);

    for (int g0 = 0; g0 < GCHUNK; g0 += 256) {
        __syncthreads();
        const float xv = xrow[g0 + tid];
        const int   iv = irow[g0 + tid];
        const float lw = log1pf(xv);
        xsum += xv;
        wsum += lw;
        lw_s[tid]  = lw;
        idx_s[tid] = iv;
        __syncthreads();

        #pragma unroll 8
        for (int k = 0; k < 64; ++k) {
            const int   gidx = (k << 2) | wave;
            const float lw_b = lw_s[gidx];
            const uint2 e    = emb2[(size_t)idx_s[gidx] * 64 + lane];
            acc.x = fmaf(lw_b, __uint_as_float(e.x << 16),         acc.x);
            acc.y = fmaf(lw_b, __uint_as_float(e.x & 0xFFFF0000u), acc.y);
            acc.z = fmaf(lw_b, __uint_as_float(e.y << 16),         acc.z);
            acc.w = fmaf(lw_b, __uint_as_float(e.y & 0xFFFF0000u), acc.w);
        }
    }

    accred[wave][lane * 4 + 0] = acc.x;
    accred[wave][lane * 4 + 1] = acc.y;
    accred[wave][lane * 4 + 2] = acc.z;
    accred[wave][lane * 4 + 3] = acc.w;

    #pragma unroll
    for (int off = 32; off > 0; off >>= 1) {
        wsum += __shfl_down(wsum, off);
        xsum += __shfl_down(xsum, off);
    }
    if (lane == 0) { redw[wave] = wsum; redx[wave] = xsum; }
    __syncthreads();

    const float tot = accred[0][tid] + accred[1][tid] + accred[2][tid] + accred[3][tid];
    ws_pool[((size_t)b * SPLIT + s) * DG + tid] = tot;
    if (tid == 0) {
        ws_wsum[b * SPLIT + s] = redw[0] + redw[1] + redw[2] + redw[3];
        ws_xsum[b * SPLIT + s] = redx[0] + redx[1] + redx[2] + redx[3];
    }
}

// ---------------------------------------------------------------------------
// MLP: combine NS partials (compile-time, unrolled) + normalize + 3-layer
// head.  One block (512 thr) per row.
// out: mu (B*64) | logvar (B*64) | h_pool (B*256)
// ---------------------------------------------------------------------------
template <int NS, int NW>
__global__ __launch_bounds__(512) void mlp_kernel(
    const float* __restrict__ part,
    const float* __restrict__ wsA, const float* __restrict__ xsA,
    const float* __restrict__ W1, const float* __restrict__ b1,
    const float* __restrict__ W2, const float* __restrict__ b2,
    const float* __restrict__ Wmu, const float* __restrict__ bmu,
    const float* __restrict__ Wlv, const float* __restrict__ blv,
    float* __restrict__ out)
{
    const int b   = blockIdx.x;
    const int tid = threadIdx.x;
    const int kq  = tid >> 6;
    const int c4  = tid & 63;

    __shared__ float  h[DH + 1];
    __shared__ float  h1[DH];
    __shared__ float  h2[DH];
    __shared__ float4 red[8][64];
    __shared__ float  redz[8][64];

    if (tid < DH) {
        float acc = 0.f;
        #pragma unroll
        for (int s = 0; s < NS; ++s)
            acc += part[((size_t)b * NS + s) * DG + tid];
        float wsum = 0.f, xsum = 0.f;
        #pragma unroll
        for (int s = 0; s < NW; ++s) {
            wsum += wsA[b * NW + s];
            xsum += xsA[b * NW + s];
        }
        const float hp = acc / (wsum + 1e-8f);
        out[2 * BB * DZ + (size_t)b * DG + tid] = hp;
        h[tid] = hp;
        if (tid == 0) h[DH] = log1pf(xsum);
    }
    __syncthreads();

    {   // layer 1: (257) @ W1(257,256), relu
        const float4* Wv = (const float4*)W1;
        float4 a = make_float4(0.f, 0.f, 0.f, 0.f);
        const int i0 = kq * 32;
        const int i1 = i0 + 32 + (kq == 7 ? 1 : 0);
        for (int i = i0; i < i1; ++i) {
            const float  hi = h[i];
            const float4 w  = Wv[(size_t)i * 64 + c4];
            a.x = fmaf(hi, w.x, a.x);
            a.y = fmaf(hi, w.y, a.y);
            a.z = fmaf(hi, w.z, a.z);
            a.w = fmaf(hi, w.w, a.w);
        }
        red[kq][c4] = a;
        __syncthreads();
        if (tid < 64) {
            float4 t = red[0][tid];
            #pragma unroll
            for (int s = 1; s < 8; ++s) {
                const float4 rr = red[s][tid];
                t.x += rr.x; t.y += rr.y; t.z += rr.z; t.w += rr.w;
            }
            const float4 bb = ((const float4*)b1)[tid];
            h1[4 * tid + 0] = fmaxf(t.x + bb.x, 0.f);
            h1[4 * tid + 1] = fmaxf(t.y + bb.y, 0.f);
            h1[4 * tid + 2] = fmaxf(t.z + bb.z, 0.f);
            h1[4 * tid + 3] = fmaxf(t.w + bb.w, 0.f);
        }
        __syncthreads();
    }

    {   // layer 2: (256) @ W2(256,256), relu
        const float4* Wv = (const float4*)W2;
        float4 a = make_float4(0.f, 0.f, 0.f, 0.f);
        const int i0 = kq * 32;
        for (int i = i0; i < i0 + 32; ++i) {
            const float  hi = h1[i];
            const float4 w  = Wv[(size_t)i * 64 + c4];
            a.x = fmaf(hi, w.x, a.x);
            a.y = fmaf(hi, w.y, a.y);
            a.z = fmaf(hi, w.z, a.z);
            a.w = fmaf(hi, w.w, a.w);
        }
        red[kq][c4] = a;
        __syncthreads();
        if (tid < 64) {
            float4 t = red[0][tid];
            #pragma unroll
            for (int s = 1; s < 8; ++s) {
                const float4 rr = red[s][tid];
                t.x += rr.x; t.y += rr.y; t.z += rr.z; t.w += rr.w;
            }
            const float4 bb = ((const float4*)b2)[tid];
            h2[4 * tid + 0] = fmaxf(t.x + bb.x, 0.f);
            h2[4 * tid + 1] = fmaxf(t.y + bb.y, 0.f);
            h2[4 * tid + 2] = fmaxf(t.z + bb.z, 0.f);
            h2[4 * tid + 3] = fmaxf(t.w + bb.w, 0.f);
        }
        __syncthreads();
    }

    {   // heads
        const bool is_lv = tid >= 256;
        const int  j  = tid & 63;
        const int  kh = (tid >> 6) & 3;
        const float* Wz = is_lv ? Wlv : Wmu;
        float az = 0.f;
        for (int i = kh * 64; i < kh * 64 + 64; ++i)
            az = fmaf(h2[i], Wz[(size_t)i * DZ + j], az);
        redz[(is_lv ? 4 : 0) + kh][j] = az;
        __syncthreads();
        if (tid < 2 * DZ) {
            const bool lv = tid >= DZ;
            const int  jj = tid & (DZ - 1);
            const int  base = lv ? 4 : 0;
            float rr = redz[base][jj] + redz[base + 1][jj]
                     + redz[base + 2][jj] + redz[base + 3][jj];
            rr += lv ? blv[jj] : bmu[jj];
            out[(lv ? BB * DZ : 0) + (size_t)b * DZ + jj] = rr;
        }
    }
}

extern "C" void kernel_launch(void* const* d_in, const int* in_sizes, int n_in,
                              void* d_out, int out_size, void* d_ws, size_t ws_size,
                              hipStream_t stream) {
    const float* x    = (const float*)d_in[0];
    const int*   gi   = (const int*)  d_in[1];
    const float* emb  = (const float*)d_in[2];
    const float* W1   = (const float*)d_in[3];
    const float* b1   = (const float*)d_in[4];
    const float* W2   = (const float*)d_in[5];
    const float* b2   = (const float*)d_in[6];
    const float* Wmu  = (const float*)d_in[7];
    const float* bmu  = (const float*)d_in[8];
    const float* Wlv  = (const float*)d_in[9];
    const float* blv  = (const float*)d_in[10];
    float* out = (float*)d_out;

    char* ws = (char*)d_ws;
    float* ws_wsum = (float*)(ws + 0);         // <= 1024 entries
    float* ws_xsum = (float*)(ws + 4096);
    const size_t off_main = 8192;

    // full GEMM path sizes
    const size_t szW   = (size_t)BB * KPAD * sizeof(unsigned short);   // 15,368,192
    const size_t szFB  = (size_t)FB_TILES * 1024;                      // 15,368,192
    const size_t szGP  = (size_t)BB * KSPLIT * DG * sizeof(float);     // 33,554,432
    const size_t szP2  = (size_t)BB * NPART2 * DG * sizeof(float);     //  2,097,152
    const size_t need_full = off_main + szW + szFB + szGP + szP2;

    // fallback sizes
    const size_t szPool = (size_t)BB * SPLIT * DG * sizeof(float);
    const size_t szEmbh = (size_t)NGENES * DG * sizeof(unsigned short);
    const size_t need_fb = off_main + szPool + szEmbh;

    if (ws_size >= need_full) {
        unsigned short* Wm    = (unsigned short*)(ws + off_main);
        unsigned short* fragB = (unsigned short*)(ws + off_main + szW);
        float*          wsg   = (float*)(ws + off_main + szW + szFB);
        float*          part2 = (float*)(ws + off_main + szW + szFB + szGP);

        scatter_kernel<<<dim3(BB, 2), 256, 0, stream>>>(x, gi, Wm, ws_wsum, ws_xsum);
        fragb_kernel<<<FB_TILES / 4, 256, 0, stream>>>(emb, fragB);
        gemm_kernel<<<dim3(4, KSPLIT), 256, 0, stream>>>(Wm, fragB, wsg);
        reduce_kernel<<<dim3(BB, NPART2), 256, 0, stream>>>(wsg, part2);
        mlp_kernel<NPART2, 1><<<BB, 512, 0, stream>>>(part2, ws_wsum, ws_xsum,
                                           W1, b1, W2, b2, Wmu, bmu, Wlv, blv, out);
    } else if (ws_size >= need_fb) {
        float*          ws_pool = (float*)(ws + off_main);
        unsigned short* embh    = (unsigned short*)(ws + off_main + szPool);

        convert_kernel<<<2048, 256, 0, stream>>>(emb, embh, NGENES * DG / 4);
        pool_bf16_kernel<<<dim3(BB, SPLIT), 256, 0, stream>>>(
            x, gi, embh, ws_pool, ws_wsum, ws_xsum);
        mlp_kernel<SPLIT, SPLIT><<<BB, 512, 0, stream>>>(ws_pool, ws_wsum, ws_xsum,
                                           W1, b1, W2, b2, Wmu, bmu, Wlv, blv, out);
    }
}